// Round 2
// baseline (47.357 us; speedup 1.0000x reference)
//
#include <hip/hip_runtime.h>
#include <math.h>

#define NJ 24
#define NV 6890
#define NB 128

__constant__ int d_parents[NJ] = {-1,0,0,0,1,2,3,4,5,6,7,8,9,9,9,12,13,14,16,17,18,19,20,21};

// Kernel 1: per-batch Rodrigues + kinematic chain + J-correction.
// Writes Gc[b][m][12] (3x4 row-major, col 3 = corrected translation) to ws.
__global__ __launch_bounds__(64) void chain_kernel(const float* __restrict__ J,
                                                   const float* __restrict__ pose,
                                                   float* __restrict__ Gc) {
    int b = blockIdx.x;
    int tid = threadIdx.x;
    __shared__ float Ar[NJ][9];
    __shared__ float At[NJ][3];
    __shared__ float G[NJ][12];

    if (tid < NJ) {
        int i = tid;
        const float* p = pose + ((size_t)b * NJ + i) * 3;
        float rx = p[0], ry = p[1], rz = p[2];
        float ex = rx + 1e-8f, ey = ry + 1e-8f, ez = rz + 1e-8f;
        float theta = sqrtf(ex * ex + ey * ey + ez * ez);
        float inv = 1.0f / theta;
        float hx = rx * inv, hy = ry * inv, hz = rz * inv;
        float c = cosf(theta * (float)M_PI);
        float s = sinf(theta);
        float oc = 1.0f - c;
        Ar[i][0] = c + oc * hx * hx;
        Ar[i][1] = oc * hx * hy - s * hz;
        Ar[i][2] = oc * hx * hz + s * hy;
        Ar[i][3] = oc * hy * hx + s * hz;
        Ar[i][4] = c + oc * hy * hy;
        Ar[i][5] = oc * hy * hz - s * hx;
        Ar[i][6] = oc * hz * hx - s * hy;
        Ar[i][7] = oc * hz * hy + s * hx;
        Ar[i][8] = c + oc * hz * hz;
        const float* jp = J + ((size_t)b * NJ + i) * 3;
        int par = d_parents[i];
        if (par < 0) {
            At[i][0] = jp[0]; At[i][1] = jp[1]; At[i][2] = jp[2];
        } else {
            const float* jq = J + ((size_t)b * NJ + par) * 3;
            At[i][0] = jp[0] - jq[0];
            At[i][1] = jp[1] - jq[1];
            At[i][2] = jp[2] - jq[2];
        }
    }
    __syncthreads();

    if (tid == 0) {
        #pragma unroll
        for (int r = 0; r < 3; r++) {
            G[0][r * 4 + 0] = Ar[0][r * 3 + 0];
            G[0][r * 4 + 1] = Ar[0][r * 3 + 1];
            G[0][r * 4 + 2] = Ar[0][r * 3 + 2];
            G[0][r * 4 + 3] = At[0][r];
        }
        for (int i = 1; i < NJ; i++) {
            int p = d_parents[i];
            #pragma unroll
            for (int r = 0; r < 3; r++) {
                float g0 = G[p][r * 4 + 0], g1 = G[p][r * 4 + 1];
                float g2 = G[p][r * 4 + 2], g3 = G[p][r * 4 + 3];
                G[i][r * 4 + 0] = g0 * Ar[i][0] + g1 * Ar[i][3] + g2 * Ar[i][6];
                G[i][r * 4 + 1] = g0 * Ar[i][1] + g1 * Ar[i][4] + g2 * Ar[i][7];
                G[i][r * 4 + 2] = g0 * Ar[i][2] + g1 * Ar[i][5] + g2 * Ar[i][8];
                G[i][r * 4 + 3] = g0 * At[i][0] + g1 * At[i][1] + g2 * At[i][2] + g3;
            }
        }
    }
    __syncthreads();

    if (tid < NJ) {
        int i = tid;
        const float* jp = J + ((size_t)b * NJ + i) * 3;
        float jx = jp[0], jy = jp[1], jz = jp[2];
        float* o = Gc + ((size_t)b * NJ + i) * 12;
        #pragma unroll
        for (int r = 0; r < 3; r++) {
            float g0 = G[i][r * 4 + 0], g1 = G[i][r * 4 + 1];
            float g2 = G[i][r * 4 + 2], g3 = G[i][r * 4 + 3];
            float corr = g0 * jx + g1 * jy + g2 * jz;
            o[r * 4 + 0] = g0;
            o[r * 4 + 1] = g1;
            o[r * 4 + 2] = g2;
            o[r * 4 + 3] = g3 - corr;
        }
    }
}

// Kernel 2: per-vertex skinning, 2 vertices per thread, float4 LDS reads.
// out[b,n] = (sum_m W[b,n,m] * Gc[b,m]) @ [V,1]
__global__ __launch_bounds__(256) void lbs_kernel(const float* __restrict__ V,
                                                  const float* __restrict__ W,
                                                  const float* __restrict__ Gc,
                                                  float* __restrict__ out) {
    int b = blockIdx.y;
    int tid = threadIdx.x;
    int n0 = blockIdx.x * 512 + tid;
    int n1 = n0 + 256;

    __shared__ float4 g4[NJ * 3];   // Gc[b] as 72 float4 (3 per joint row-group)
    if (tid < NJ * 3)
        g4[tid] = ((const float4*)(Gc + (size_t)b * NJ * 12))[tid];
    __syncthreads();

    if (n0 >= NV) return;
    bool has1 = (n1 < NV);

    // Load W rows (24 floats each) as 6 float4
    const float4* wp0 = (const float4*)(W + ((size_t)b * NV + n0) * 24);
    float wa[24], wb[24];
    #pragma unroll
    for (int k = 0; k < 6; k++) {
        float4 t = wp0[k];
        wa[4 * k + 0] = t.x; wa[4 * k + 1] = t.y; wa[4 * k + 2] = t.z; wa[4 * k + 3] = t.w;
    }
    if (has1) {
        const float4* wp1 = (const float4*)(W + ((size_t)b * NV + n1) * 24);
        #pragma unroll
        for (int k = 0; k < 6; k++) {
            float4 t = wp1[k];
            wb[4 * k + 0] = t.x; wb[4 * k + 1] = t.y; wb[4 * k + 2] = t.z; wb[4 * k + 3] = t.w;
        }
    } else {
        #pragma unroll
        for (int k = 0; k < 24; k++) wb[k] = 0.0f;
    }

    float4 Ta0 = {0,0,0,0}, Ta1 = {0,0,0,0}, Ta2 = {0,0,0,0};
    float4 Tb0 = {0,0,0,0}, Tb1 = {0,0,0,0}, Tb2 = {0,0,0,0};
    #pragma unroll
    for (int m = 0; m < NJ; m++) {
        float4 g0 = g4[m * 3 + 0];
        float4 g1 = g4[m * 3 + 1];
        float4 g2 = g4[m * 3 + 2];
        float ua = wa[m], ub = wb[m];
        Ta0.x += ua * g0.x; Ta0.y += ua * g0.y; Ta0.z += ua * g0.z; Ta0.w += ua * g0.w;
        Ta1.x += ua * g1.x; Ta1.y += ua * g1.y; Ta1.z += ua * g1.z; Ta1.w += ua * g1.w;
        Ta2.x += ua * g2.x; Ta2.y += ua * g2.y; Ta2.z += ua * g2.z; Ta2.w += ua * g2.w;
        Tb0.x += ub * g0.x; Tb0.y += ub * g0.y; Tb0.z += ub * g0.z; Tb0.w += ub * g0.w;
        Tb1.x += ub * g1.x; Tb1.y += ub * g1.y; Tb1.z += ub * g1.z; Tb1.w += ub * g1.w;
        Tb2.x += ub * g2.x; Tb2.y += ub * g2.y; Tb2.z += ub * g2.z; Tb2.w += ub * g2.w;
    }

    {
        const float* vp = V + ((size_t)b * NV + n0) * 3;
        float vx = vp[0], vy = vp[1], vz = vp[2];
        float* op = out + ((size_t)b * NV + n0) * 3;
        op[0] = Ta0.x * vx + Ta0.y * vy + Ta0.z * vz + Ta0.w;
        op[1] = Ta1.x * vx + Ta1.y * vy + Ta1.z * vz + Ta1.w;
        op[2] = Ta2.x * vx + Ta2.y * vy + Ta2.z * vz + Ta2.w;
    }
    if (has1) {
        const float* vp = V + ((size_t)b * NV + n1) * 3;
        float vx = vp[0], vy = vp[1], vz = vp[2];
        float* op = out + ((size_t)b * NV + n1) * 3;
        op[0] = Tb0.x * vx + Tb0.y * vy + Tb0.z * vz + Tb0.w;
        op[1] = Tb1.x * vx + Tb1.y * vy + Tb1.z * vz + Tb1.w;
        op[2] = Tb2.x * vx + Tb2.y * vy + Tb2.z * vz + Tb2.w;
    }
}

extern "C" void kernel_launch(void* const* d_in, const int* in_sizes, int n_in,
                              void* d_out, int out_size, void* d_ws, size_t ws_size,
                              hipStream_t stream) {
    const float* V    = (const float*)d_in[0];
    const float* J    = (const float*)d_in[1];
    const float* pose = (const float*)d_in[2];
    const float* W    = (const float*)d_in[3];
    float* out = (float*)d_out;
    float* Gc  = (float*)d_ws;  // NB*NJ*12 floats = 147456 B

    chain_kernel<<<NB, 64, 0, stream>>>(J, pose, Gc);
    dim3 grid((NV + 511) / 512, NB);
    lbs_kernel<<<grid, 256, 0, stream>>>(V, W, Gc, out);
}

// Round 3
// 32.388 us; speedup vs baseline: 1.4622x; 1.4622x over previous
//
#include <hip/hip_runtime.h>
#include <math.h>

#define NJ 24
#define NV 6890
#define NB 128

__constant__ int d_parents[NJ] = {-1,0,0,0,1,2,3,4,5,6,7,8,9,9,9,12,13,14,16,17,18,19,20,21};

// Kernel 1: per-batch Rodrigues + kinematic chain + J-correction.
// Writes Gc[b][m][12] (3x4 row-major, col 3 = corrected translation) to ws.
__global__ __launch_bounds__(64) void chain_kernel(const float* __restrict__ J,
                                                   const float* __restrict__ pose,
                                                   float* __restrict__ Gc) {
    int b = blockIdx.x;
    int tid = threadIdx.x;
    __shared__ float Ar[NJ][9];
    __shared__ float At[NJ][3];
    __shared__ float G[NJ][12];

    if (tid < NJ) {
        int i = tid;
        const float* p = pose + ((size_t)b * NJ + i) * 3;
        float rx = p[0], ry = p[1], rz = p[2];
        float ex = rx + 1e-8f, ey = ry + 1e-8f, ez = rz + 1e-8f;
        float theta = sqrtf(ex * ex + ey * ey + ez * ez);
        float inv = 1.0f / theta;
        float hx = rx * inv, hy = ry * inv, hz = rz * inv;
        float c = cosf(theta * (float)M_PI);
        float s = sinf(theta);
        float oc = 1.0f - c;
        Ar[i][0] = c + oc * hx * hx;
        Ar[i][1] = oc * hx * hy - s * hz;
        Ar[i][2] = oc * hx * hz + s * hy;
        Ar[i][3] = oc * hy * hx + s * hz;
        Ar[i][4] = c + oc * hy * hy;
        Ar[i][5] = oc * hy * hz - s * hx;
        Ar[i][6] = oc * hz * hx - s * hy;
        Ar[i][7] = oc * hz * hy + s * hx;
        Ar[i][8] = c + oc * hz * hz;
        const float* jp = J + ((size_t)b * NJ + i) * 3;
        int par = d_parents[i];
        if (par < 0) {
            At[i][0] = jp[0]; At[i][1] = jp[1]; At[i][2] = jp[2];
        } else {
            const float* jq = J + ((size_t)b * NJ + par) * 3;
            At[i][0] = jp[0] - jq[0];
            At[i][1] = jp[1] - jq[1];
            At[i][2] = jp[2] - jq[2];
        }
    }
    __syncthreads();

    if (tid == 0) {
        #pragma unroll
        for (int r = 0; r < 3; r++) {
            G[0][r * 4 + 0] = Ar[0][r * 3 + 0];
            G[0][r * 4 + 1] = Ar[0][r * 3 + 1];
            G[0][r * 4 + 2] = Ar[0][r * 3 + 2];
            G[0][r * 4 + 3] = At[0][r];
        }
        for (int i = 1; i < NJ; i++) {
            int p = d_parents[i];
            #pragma unroll
            for (int r = 0; r < 3; r++) {
                float g0 = G[p][r * 4 + 0], g1 = G[p][r * 4 + 1];
                float g2 = G[p][r * 4 + 2], g3 = G[p][r * 4 + 3];
                G[i][r * 4 + 0] = g0 * Ar[i][0] + g1 * Ar[i][3] + g2 * Ar[i][6];
                G[i][r * 4 + 1] = g0 * Ar[i][1] + g1 * Ar[i][4] + g2 * Ar[i][7];
                G[i][r * 4 + 2] = g0 * Ar[i][2] + g1 * Ar[i][5] + g2 * Ar[i][8];
                G[i][r * 4 + 3] = g0 * At[i][0] + g1 * At[i][1] + g2 * At[i][2] + g3;
            }
        }
    }
    __syncthreads();

    if (tid < NJ) {
        int i = tid;
        const float* jp = J + ((size_t)b * NJ + i) * 3;
        float jx = jp[0], jy = jp[1], jz = jp[2];
        float* o = Gc + ((size_t)b * NJ + i) * 12;
        #pragma unroll
        for (int r = 0; r < 3; r++) {
            float g0 = G[i][r * 4 + 0], g1 = G[i][r * 4 + 1];
            float g2 = G[i][r * 4 + 2], g3 = G[i][r * 4 + 3];
            float corr = g0 * jx + g1 * jy + g2 * jz;
            o[r * 4 + 0] = g0;
            o[r * 4 + 1] = g1;
            o[r * 4 + 2] = g2;
            o[r * 4 + 3] = g3 - corr;
        }
    }
}

// Kernel 2: per-vertex skinning, 1 vertex/thread.
// Gc[b] is wave-uniform -> compiler scalarizes to s_load; blend is
// v_fmac_f32 v,s,v. No LDS, no __syncthreads, low VGPR -> high occupancy.
__global__ __launch_bounds__(256) void lbs_kernel(const float* __restrict__ V,
                                                  const float* __restrict__ W,
                                                  const float* __restrict__ Gc,
                                                  float* __restrict__ out) {
    const int b = blockIdx.y;
    const int n = blockIdx.x * 256 + threadIdx.x;
    if (n >= NV) return;

    const float* __restrict__ gb = Gc + (size_t)b * (NJ * 12);  // uniform address

    const float4* wp = (const float4*)(W + ((size_t)b * NV + n) * 24);
    float w[24];
    #pragma unroll
    for (int k = 0; k < 6; k++) {
        float4 t = wp[k];
        w[4 * k + 0] = t.x; w[4 * k + 1] = t.y; w[4 * k + 2] = t.z; w[4 * k + 3] = t.w;
    }

    float T[12];
    #pragma unroll
    for (int j = 0; j < 12; j++) T[j] = 0.0f;

    #pragma unroll
    for (int m = 0; m < NJ; m++) {
        float wm = w[m];
        #pragma unroll
        for (int j = 0; j < 12; j++)
            T[j] = fmaf(wm, gb[m * 12 + j], T[j]);
    }

    const float* vp = V + ((size_t)b * NV + n) * 3;
    float vx = vp[0], vy = vp[1], vz = vp[2];
    float* op = out + ((size_t)b * NV + n) * 3;
    op[0] = T[0] * vx + T[1] * vy + T[2]  * vz + T[3];
    op[1] = T[4] * vx + T[5] * vy + T[6]  * vz + T[7];
    op[2] = T[8] * vx + T[9] * vy + T[10] * vz + T[11];
}

extern "C" void kernel_launch(void* const* d_in, const int* in_sizes, int n_in,
                              void* d_out, int out_size, void* d_ws, size_t ws_size,
                              hipStream_t stream) {
    const float* V    = (const float*)d_in[0];
    const float* J    = (const float*)d_in[1];
    const float* pose = (const float*)d_in[2];
    const float* W    = (const float*)d_in[3];
    float* out = (float*)d_out;
    float* Gc  = (float*)d_ws;  // NB*NJ*12 floats = 147456 B

    chain_kernel<<<NB, 64, 0, stream>>>(J, pose, Gc);
    dim3 grid((NV + 255) / 256, NB);
    lbs_kernel<<<grid, 256, 0, stream>>>(V, W, Gc, out);
}